// Round 8
// baseline (251.494 us; speedup 1.0000x reference)
//
#include <hip/hip_runtime.h>

// Problem: img [B=256, C=3, H=224, W=224] f32; zero a 32x32 square per batch
// (all channels), copy the rest. ~308 MB traffic.
//
// Rounds 0-6 eliminated: wave structure, forced MLP (asm burst r5, counted
// rolling window r6), occupancy, grid shape, SDMA (r4), HBM byte count.
// Round 7 (nt LOADS on the r0 one-shot structure): 255.8 -> 250.9 us total,
// kernel ~65 us @ ~4.7 TB/s -- L1-bypass on the zero-reuse read stream is
// real. This round adds the last untested single variable: nt STORES.
// Mechanism: plain stores write-allocate in L2 (4 MiB/XCD); 154 MB of write
// allocations sweep L2 and their evictions contend with the read stream.
// r1's nt-store regression was confounded (load batch sunk to MLP=1).
//
// Base: round-7 kernel verbatim; only the store changes.

#define SQ 32
#define B_ 256
#define C_ 3
#define H_ 224
#define W_ 224

typedef float v4f __attribute__((ext_vector_type(4)));

__global__ __launch_bounds__(256) void rsd_kernel(const v4f* __restrict__ img,
                                                  const int* __restrict__ y_idx,
                                                  const int* __restrict__ x_idx,
                                                  v4f* __restrict__ out,
                                                  int total4) {
    int i4 = blockIdx.x * 256 + threadIdx.x;
    if (i4 >= total4) return;

    // Non-temporal load: zero-reuse stream, no L1 allocation (r7: -5 us).
    v4f v = __builtin_nontemporal_load(&img[i4]);

    int i = i4 << 2;                 // flat element index of lane 0 of this float4
    int w = i % W_;                  // column of first element (W%4==0: same row)
    int t = i / W_;                  // row index within [B*C*H]
    int h = t % H_;
    int b = t / (C_ * H_);

    int y0 = y_idx[b];
    int x0 = x_idx[b];

    if ((unsigned)(h - y0) < SQ) {   // row inside square?
        int cx = w - x0;
        if ((unsigned)(cx + 0) < SQ) v.x = 0.0f;
        if ((unsigned)(cx + 1) < SQ) v.y = 0.0f;
        if ((unsigned)(cx + 2) < SQ) v.z = 0.0f;
        if ((unsigned)(cx + 3) < SQ) v.w = 0.0f;
    }

    // Non-temporal store: keep the 154 MB write stream from write-allocating
    // in L2 / generating eviction traffic against the read stream.
    __builtin_nontemporal_store(v, &out[i4]);
}

extern "C" void kernel_launch(void* const* d_in, const int* in_sizes, int n_in,
                              void* d_out, int out_size, void* d_ws, size_t ws_size,
                              hipStream_t stream) {
    const v4f* img  = (const v4f*)d_in[0];
    const int* yidx = (const int*)d_in[1];
    const int* xidx = (const int*)d_in[2];
    v4f*       out  = (v4f*)d_out;

    int total4 = out_size / 4;       // out_size is ELEMENT count; 9,633,792 float4
    int blocks = (total4 + 255) / 256;
    rsd_kernel<<<blocks, 256, 0, stream>>>(img, yidx, xidx, out, total4);
}